// Round 1
// baseline (226.035 us; speedup 1.0000x reference)
//
#include <hip/hip_runtime.h>

// ---------- types ----------
typedef __bf16 bf16x8v __attribute__((ext_vector_type(8)));
typedef float f32x4v __attribute__((ext_vector_type(4)));
typedef unsigned short u16x8 __attribute__((ext_vector_type(8)));

__device__ inline unsigned short f2bf(float f) {
  union { float f; unsigned u; } a; a.f = f;
  return (unsigned short)((a.u + 0x7fffu + ((a.u >> 16) & 1u)) >> 16); // RNE
}
__device__ inline float bf2f(unsigned short h) {
  union { unsigned u; float f; } a; a.u = ((unsigned)h) << 16;
  return a.f;
}

// ---------- fp32 -> bf16 conversion (query,key,value,Wq,Wk,Wv) ----------
struct CvtArgs {
  const float* src[6];
  unsigned short* dst[6];
};

// totals: 3 x 8388608 (X) + 3 x 1048576 (W) elements; as float4: 3*2^21 + 3*2^18
__global__ __launch_bounds__(256) void cvt6(CvtArgs a) {
  long long i = (long long)blockIdx.x * 256 + threadIdx.x; // one float4 each
  int idx; long long off;
  if (i < 6291456LL) { idx = (int)(i >> 21); off = i & ((1LL << 21) - 1); }
  else { long long j = i - 6291456LL; idx = 3 + (int)(j >> 18); off = j & ((1LL << 18) - 1); }
  float4 v = ((const float4*)a.src[idx])[off];
  ushort4 o;
  o.x = f2bf(v.x); o.y = f2bf(v.y); o.z = f2bf(v.z); o.w = f2bf(v.w);
  ((ushort4*)a.dst[idx])[off] = o;
}

// ---------- B^T-layout bf16 GEMM: C[M,N] = A[M,K] * B[N,K]^T ----------
// 128x128 tile, BK=64, 256 threads (4 waves, 2x2), each wave 64x64 via 4x4
// frags of v_mfma_f32_16x16x32_bf16. m97-style: global_load_lds staging,
// 2 barriers per K-step.
#define EPI_BIAS 0   // + bias[col], bf16 out, row-major
#define EPI_TRANS 1  // + bias[col], bf16 out TRANSPOSED per batch: vT[b][col][row]
#define EPI_SCALE 2  // * scale, bf16 out row-major
#define EPI_OUT 3    // fp32 out row-major

template<int EPI>
__global__ __launch_bounds__(256, 2) void gemm_bt(
    const unsigned short* __restrict__ A,
    const unsigned short* __restrict__ B,
    void* __restrict__ Cv,
    const float* __restrict__ bias,
    int lda, int ldb, int ldc, int K, float scale,
    long long batchA, long long batchB, long long batchC)
{
  __shared__ unsigned short sA[128 * 64];
  __shared__ unsigned short sB[128 * 64];
  const int tid = threadIdx.x;
  const int lane = tid & 63;
  const int wave = tid >> 6;
  const int wm = wave >> 1, wn = wave & 1;
  const int z = blockIdx.z;
  const int m0 = blockIdx.y * 128, n0 = blockIdx.x * 128;

  const char* Ab = (const char*)(A + (long long)z * batchA + (long long)m0 * lda);
  const char* Bb = (const char*)(B + (long long)z * batchB + (long long)n0 * ldb);
  const int lda2 = lda * 2, ldb2 = ldb * 2;

  f32x4v acc[4][4];
#pragma unroll
  for (int i = 0; i < 4; ++i)
#pragma unroll
    for (int j = 0; j < 4; ++j) acc[i][j] = (f32x4v){0.f, 0.f, 0.f, 0.f};

  // lane-derived LDS fragment offset: row=(lane&15), k16=(lane>>4)*16 bytes
  const int laneoff = (lane & 15) * 128 + (lane >> 4) * 16;

  const int nkt = K >> 6;
  for (int kt = 0; kt < nkt; ++kt) {
    const int kb = kt * 128; // K-window byte offset in a row
    // ---- stage A,B tiles (16 KB each) via async global->LDS, 16B/lane ----
#pragma unroll
    for (int i = 0; i < 4; ++i) {
      unsigned o = (unsigned)(i * 4096 + wave * 1024 + lane * 16);
      unsigned row = o >> 7, cb = o & 127u;
      __builtin_amdgcn_global_load_lds(
          (const __attribute__((address_space(1))) void*)(Ab + (long long)row * lda2 + kb + cb),
          (__attribute__((address_space(3))) void*)((char*)sA + i * 4096 + wave * 1024),
          16, 0, 0);
      __builtin_amdgcn_global_load_lds(
          (const __attribute__((address_space(1))) void*)(Bb + (long long)row * ldb2 + kb + cb),
          (__attribute__((address_space(3))) void*)((char*)sB + i * 4096 + wave * 1024),
          16, 0, 0);
    }
    __syncthreads(); // drains vmcnt -> tiles ready

    const char* sAc = (const char*)sA;
    const char* sBc = (const char*)sB;
#pragma unroll
    for (int kk = 0; kk < 2; ++kk) {
      bf16x8v af[4], bfr[4];
#pragma unroll
      for (int mi = 0; mi < 4; ++mi)
        af[mi] = *(const bf16x8v*)(sAc + (wm * 64 + mi * 16) * 128 + kk * 64 + laneoff);
#pragma unroll
      for (int ni = 0; ni < 4; ++ni)
        bfr[ni] = *(const bf16x8v*)(sBc + (wn * 64 + ni * 16) * 128 + kk * 64 + laneoff);
#pragma unroll
      for (int mi = 0; mi < 4; ++mi)
#pragma unroll
        for (int ni = 0; ni < 4; ++ni)
          acc[mi][ni] = __builtin_amdgcn_mfma_f32_16x16x32_bf16(af[mi], bfr[ni], acc[mi][ni], 0, 0, 0);
    }
    __syncthreads(); // all reads done before next stage overwrites
  }

  // ---- epilogue ----
  const int col16 = lane & 15;
  const int r0 = (lane >> 4) * 4;
  if constexpr (EPI == EPI_BIAS || EPI == EPI_SCALE || EPI == EPI_OUT) {
#pragma unroll
    for (int mi = 0; mi < 4; ++mi) {
#pragma unroll
      for (int ni = 0; ni < 4; ++ni) {
        const int gcol = n0 + wn * 64 + ni * 16 + col16;
        const float badd = (EPI == EPI_BIAS) ? bias[gcol] : 0.f;
#pragma unroll
        for (int r = 0; r < 4; ++r) {
          const int grow = m0 + wm * 64 + mi * 16 + r0 + r;
          const float val = acc[mi][ni][r] * scale + badd;
          const size_t off = (size_t)z * batchC + (size_t)grow * ldc + gcol;
          if constexpr (EPI == EPI_OUT) ((float*)Cv)[off] = val;
          else ((unsigned short*)Cv)[off] = f2bf(val);
        }
      }
    }
  } else { // EPI_TRANS: vT[b][d][s] = C[row=(b,s)][col=d] + bias[d]
#pragma unroll
    for (int mi = 0; mi < 4; ++mi) {
      const int grow0 = m0 + wm * 64 + mi * 16 + r0; // 4 consecutive rows
      const int b = grow0 >> 11;        // rows-per-batch = 2048
      const int s = grow0 & 2047;
#pragma unroll
      for (int ni = 0; ni < 4; ++ni) {
        const int d = n0 + wn * 64 + ni * 16 + col16;
        const float badd = bias[d];
        ushort4 pk;
        pk.x = f2bf(acc[mi][ni][0] + badd);
        pk.y = f2bf(acc[mi][ni][1] + badd);
        pk.z = f2bf(acc[mi][ni][2] + badd);
        pk.w = f2bf(acc[mi][ni][3] + badd);
        *(ushort4*)((unsigned short*)Cv + ((size_t)b << 21) + (size_t)d * 2048 + s) = pk;
      }
    }
  }
}

// ---------- row softmax over S[4][2048][2048] (bf16, in place) ----------
__global__ __launch_bounds__(256) void softmax_rows(unsigned short* __restrict__ S) {
  const size_t row = blockIdx.x;
  unsigned short* p = S + row * 2048;
  const int t = threadIdx.x, lane = t & 63, wave = t >> 6;
  u16x8 h = ((const u16x8*)p)[t];
  float x[8];
#pragma unroll
  for (int j = 0; j < 8; ++j) x[j] = bf2f(h[j]);
  float m = x[0];
#pragma unroll
  for (int j = 1; j < 8; ++j) m = fmaxf(m, x[j]);
#pragma unroll
  for (int off = 32; off >= 1; off >>= 1) m = fmaxf(m, __shfl_xor(m, off, 64));
  __shared__ float rmax[4], rsum[4];
  if (lane == 0) rmax[wave] = m;
  __syncthreads();
  m = fmaxf(fmaxf(rmax[0], rmax[1]), fmaxf(rmax[2], rmax[3]));
  float e[8], sum = 0.f;
#pragma unroll
  for (int j = 0; j < 8; ++j) { e[j] = __expf(x[j] - m); sum += e[j]; }
#pragma unroll
  for (int off = 32; off >= 1; off >>= 1) sum += __shfl_xor(sum, off, 64);
  if (lane == 0) rsum[wave] = sum;
  __syncthreads();
  sum = rsum[0] + rsum[1] + rsum[2] + rsum[3];
  const float inv = 1.f / sum;
  u16x8 o;
#pragma unroll
  for (int j = 0; j < 8; ++j) o[j] = f2bf(e[j] * inv);
  ((u16x8*)p)[t] = o;
}

// ---------- launch ----------
extern "C" void kernel_launch(void* const* d_in, const int* in_sizes, int n_in,
                              void* d_out, int out_size, void* d_ws, size_t ws_size,
                              hipStream_t stream) {
  const float* q  = (const float*)d_in[0];
  const float* k  = (const float*)d_in[1];
  const float* v  = (const float*)d_in[2];
  const float* Wq = (const float*)d_in[3];
  const float* bq = (const float*)d_in[4];
  const float* Wk = (const float*)d_in[5];
  const float* bk = (const float*)d_in[6];
  const float* Wv = (const float*)d_in[7];
  const float* bv = (const float*)d_in[8];

  // workspace layout (u16 elements):
  //   [0 .. 25165824)            Xb: query,key,value bf16 (48 MB)  [dead after proj]
  //   [0 .. 16777216)            S : scores/P bf16 (32 MB)         [overlaps dead Xb]
  //   [25165824 .. 28311552)     Wb: Wq,Wk,Wv bf16 (6 MB)
  //   [28311552 .. 36700160)     qb (16 MB)
  //   [36700160 .. 45088768)     kb (16 MB)
  //   [45088768 .. 53477376)     vT (16 MB)  -- total 102 MB
  unsigned short* Xb = (unsigned short*)d_ws;
  unsigned short* Wb = Xb + 25165824;
  unsigned short* qb = Wb + 3145728;
  unsigned short* kb = qb + 8388608;
  unsigned short* vT = kb + 8388608;
  unsigned short* S  = Xb;

  CvtArgs ca;
  ca.src[0] = q;  ca.src[1] = k;  ca.src[2] = v;
  ca.src[3] = Wq; ca.src[4] = Wk; ca.src[5] = Wv;
  ca.dst[0] = Xb;            ca.dst[1] = Xb + 8388608; ca.dst[2] = Xb + 16777216;
  ca.dst[3] = Wb;            ca.dst[4] = Wb + 1048576; ca.dst[5] = Wb + 2097152;
  cvt6<<<27648, 256, 0, stream>>>(ca);

  // projections: M=8192 (B*S), N=1024, K=1024
  gemm_bt<EPI_BIAS><<<dim3(8, 64, 1), 256, 0, stream>>>(
      Xb, Wb, qb, bq, 1024, 1024, 1024, 1024, 1.f, 0, 0, 0);
  gemm_bt<EPI_BIAS><<<dim3(8, 64, 1), 256, 0, stream>>>(
      Xb + 8388608, Wb + 1048576, kb, bk, 1024, 1024, 1024, 1024, 1.f, 0, 0, 0);
  gemm_bt<EPI_TRANS><<<dim3(8, 64, 1), 256, 0, stream>>>(
      Xb + 16777216, Wb + 2097152, vT, bv, 1024, 1024, 2048, 1024, 1.f, 0, 0, 0);

  // scores = q @ k^T * scale : per batch M=2048,N=2048,K=1024
  gemm_bt<EPI_SCALE><<<dim3(16, 16, 4), 256, 0, stream>>>(
      qb, kb, S, nullptr, 1024, 1024, 2048, 1024, 0.03125f,
      2097152LL, 2097152LL, 4194304LL);

  softmax_rows<<<8192, 256, 0, stream>>>(S);

  // out = P @ V = P[2048,2048] * vT[1024,2048]^T : M=2048,N=1024,K=2048
  gemm_bt<EPI_OUT><<<dim3(8, 16, 4), 256, 0, stream>>>(
      S, vT, (float*)d_out, nullptr, 2048, 2048, 1024, 2048, 1.f,
      4194304LL, 2097152LL, 2097152LL);
}

// Round 2
// 199.384 us; speedup vs baseline: 1.1337x; 1.1337x over previous
//
#include <hip/hip_runtime.h>

// ---------- types ----------
typedef __bf16 bf16x8 __attribute__((ext_vector_type(8)));
typedef float f32x4 __attribute__((ext_vector_type(4)));
typedef unsigned short u16x8 __attribute__((ext_vector_type(8)));

__device__ inline unsigned short f2bf(float f) {
  union { float f; unsigned u; } a; a.f = f;
  return (unsigned short)((a.u + 0x7fffu + ((a.u >> 16) & 1u)) >> 16); // RNE
}
__device__ inline float bf2f(unsigned short h) {
  union { unsigned u; float f; } a; a.u = ((unsigned)h) << 16;
  return a.f;
}

// ---------- fp32 -> bf16 conversion (query,key,value,Wq,Wk,Wv) ----------
struct CvtArgs {
  const float* src[6];
  unsigned short* dst[6];
};

__global__ __launch_bounds__(256) void cvt6(CvtArgs a) {
  long long i = (long long)blockIdx.x * 256 + threadIdx.x; // one float4 each
  int idx; long long off;
  if (i < 6291456LL) { idx = (int)(i >> 21); off = i & ((1LL << 21) - 1); }
  else { long long j = i - 6291456LL; idx = 3 + (int)(j >> 18); off = j & ((1LL << 18) - 1); }
  float4 v = ((const float4*)a.src[idx])[off];
  ushort4 o;
  o.x = f2bf(v.x); o.y = f2bf(v.y); o.z = f2bf(v.z); o.w = f2bf(v.w);
  ((ushort4*)a.dst[idx])[off] = o;
}

// =====================================================================
// 256x256 8-phase GEMM (T2+T3+T4+T5): C[M,N] = A[M,K] @ B[N,K]^T, bf16.
// 512 threads = 8 waves (2M x 4N), per-wave 128x64 out, BK=64.
// LDS 128KB: A bufs [0,64K), B bufs [64K,128K), double-buffered.
// Staging: global_load_lds (linear dest) + inverse-swizzled global source;
// reads use XOR swizzle (row&7)<<4 -> conflict-free ds_read_b128.
// Counted vmcnt(8) once per K-tile (prefetch runs 2 tiles ahead).
// =====================================================================
#define EPI_PROJ 0
#define EPI_SCALE 1

struct G256 {
  const unsigned short* A;
  const unsigned short* B;
  unsigned short* C;
  unsigned short* outQ; unsigned short* outK; unsigned short* outV;
  const float* biasQ; const float* biasK; const float* biasV;
  long long batchA, batchB, batchC;
  int lda, ldb, ldc, K;
  float scale;
};

#define G2L(gp, lp) __builtin_amdgcn_global_load_lds( \
    (const __attribute__((address_space(1))) void*)(gp), \
    (__attribute__((address_space(3))) void*)(lp), 16, 0, 0)

#define MFMA_(d, a, b) d = __builtin_amdgcn_mfma_f32_16x16x32_bf16(a, b, d, 0, 0, 0)

template<int EPI>
__global__ __launch_bounds__(512, 2) void gemm256(G256 p) {
  extern __shared__ char smem[]; // 131072 bytes
  char* smA = smem;
  char* smB = smem + 65536;

  const int tid = threadIdx.x;
  const int lane = tid & 63;
  const int wave = tid >> 6;
  const int wm = wave >> 2;   // 0..1
  const int wn = wave & 3;    // 0..3

  // bijective XCD-aware block swizzle (m204 variant)
  const int gx = gridDim.x, gy = gridDim.y;
  const int nwg = gx * gy * (int)gridDim.z;
  int orig = blockIdx.x + gx * (blockIdx.y + gy * blockIdx.z);
  int q = nwg >> 3, r = nwg & 7;
  int xcd = orig & 7, sl = orig >> 3;
  int wg = (xcd < r ? xcd * (q + 1) : r * (q + 1) + (xcd - r) * q) + sl;
  int bx = wg % gx;
  int t2 = wg / gx;
  int by = t2 % gy;
  int z  = t2 / gy;

  const int m0 = by << 8, n0 = bx << 8;

  const long long lda2 = (long long)p.lda * 2;
  const long long ldb2 = (long long)p.ldb * 2;
  const char* Abase = (const char*)(p.A + (long long)z * p.batchA) + (long long)m0 * lda2;
  const char* Bbase = (const char*)(p.B + (long long)z * p.batchB) + (long long)n0 * ldb2;

  // staging: thread tid covers LDS linear slot c*8192 + tid*16 (c=0..3);
  // row = c*64 + tid/8, source col = (tid&7)*16 XOR ((row&7)<<4)
  const int trow = tid >> 3;
  const int cs = (((tid & 7) ^ (trow & 7)) << 4);
  const char* srcA = Abase + (long long)trow * lda2 + cs;
  const char* srcB = Bbase + (long long)trow * ldb2 + cs;

  const int NT = p.K >> 6;

  // ds_read offsets (swizzled): frag(row, kk) at row*128 + (col ^ (row&7)<<4)
  const int arow = ((wm << 7) + (lane & 15)) << 7;
  const int brow = ((wn << 6) + (lane & 15)) << 7;
  const int csw = (lane & 7) << 4;
  const int ck0 = (((lane >> 4) << 4)) ^ csw;
  const int ck1 = ((((lane >> 4) << 4)) | 64) ^ csw;

  f32x4 acc[8][4];
#pragma unroll
  for (int i = 0; i < 8; ++i)
#pragma unroll
    for (int j = 0; j < 4; ++j) acc[i][j] = (f32x4){0.f, 0.f, 0.f, 0.f};

  bf16x8 af[4][2], bfr[4][2];

  auto issueB = [&](int t) {
    char* d = smB + ((t & 1) << 15) + (wave << 10);
    const char* s = srcB + (long long)t * 128;
#pragma unroll
    for (int c = 0; c < 4; ++c)
      G2L(s + (long long)c * (ldb2 << 6), d + (c << 13));
  };
  auto issueA = [&](int t) {
    char* d = smA + ((t & 1) << 15) + (wave << 10);
    const char* s = srcA + (long long)t * 128;
#pragma unroll
    for (int c = 0; c < 4; ++c)
      G2L(s + (long long)c * (lda2 << 6), d + (c << 13));
  };

  // prologue: stage tiles 0 and 1; wait tile 0 landed (counted)
  issueB(0); issueA(0); issueB(1); issueA(1);
  asm volatile("s_waitcnt vmcnt(8)" ::: "memory");
  __builtin_amdgcn_s_barrier();

  auto step = [&](int t, int b) {
    const char* ra = smA + (b << 15);
    const char* rb = smB + (b << 15);
    // ---------- phase 0: read A(mi0-3), B(ni0-1); MFMA mi0-3 x ni0-1 ----
#pragma unroll
    for (int mi = 0; mi < 4; ++mi) {
      af[mi][0] = *(const bf16x8*)(ra + arow + (mi << 11) + ck0);
      af[mi][1] = *(const bf16x8*)(ra + arow + (mi << 11) + ck1);
    }
#pragma unroll
    for (int ni = 0; ni < 2; ++ni) {
      bfr[ni][0] = *(const bf16x8*)(rb + brow + (ni << 11) + ck0);
      bfr[ni][1] = *(const bf16x8*)(rb + brow + (ni << 11) + ck1);
    }
    __builtin_amdgcn_s_barrier();
    asm volatile("s_waitcnt lgkmcnt(0)" ::: "memory");
    __builtin_amdgcn_sched_barrier(0);
    __builtin_amdgcn_s_setprio(1);
#pragma unroll
    for (int mi = 0; mi < 4; ++mi)
#pragma unroll
      for (int ni = 0; ni < 2; ++ni) {
        MFMA_(acc[mi][ni], af[mi][0], bfr[ni][0]);
        MFMA_(acc[mi][ni], af[mi][1], bfr[ni][1]);
      }
    __builtin_amdgcn_s_setprio(0);
    __builtin_amdgcn_s_barrier();
    // ---------- phase 1: read B(ni2-3); MFMA mi0-3 x ni2-3 --------------
#pragma unroll
    for (int ni = 2; ni < 4; ++ni) {
      bfr[ni][0] = *(const bf16x8*)(rb + brow + (ni << 11) + ck0);
      bfr[ni][1] = *(const bf16x8*)(rb + brow + (ni << 11) + ck1);
    }
    __builtin_amdgcn_s_barrier();
    asm volatile("s_waitcnt lgkmcnt(0)" ::: "memory");
    __builtin_amdgcn_sched_barrier(0);
    __builtin_amdgcn_s_setprio(1);
#pragma unroll
    for (int mi = 0; mi < 4; ++mi)
#pragma unroll
      for (int ni = 2; ni < 4; ++ni) {
        MFMA_(acc[mi][ni], af[mi][0], bfr[ni][0]);
        MFMA_(acc[mi][ni], af[mi][1], bfr[ni][1]);
      }
    __builtin_amdgcn_s_setprio(0);
    __builtin_amdgcn_s_barrier();
    // ---------- phase 2: read A(mi4-7); issue B(t+2); MFMA mi4-7 x ni0-1
#pragma unroll
    for (int mi = 0; mi < 4; ++mi) {
      af[mi][0] = *(const bf16x8*)(ra + arow + ((mi + 4) << 11) + ck0);
      af[mi][1] = *(const bf16x8*)(ra + arow + ((mi + 4) << 11) + ck1);
    }
    if (t + 2 < NT) issueB(t + 2);
    __builtin_amdgcn_s_barrier();
    asm volatile("s_waitcnt lgkmcnt(0)" ::: "memory");
    __builtin_amdgcn_sched_barrier(0);
    __builtin_amdgcn_s_setprio(1);
#pragma unroll
    for (int mi = 0; mi < 4; ++mi)
#pragma unroll
      for (int ni = 0; ni < 2; ++ni) {
        MFMA_(acc[mi + 4][ni], af[mi][0], bfr[ni][0]);
        MFMA_(acc[mi + 4][ni], af[mi][1], bfr[ni][1]);
      }
    __builtin_amdgcn_s_setprio(0);
    __builtin_amdgcn_s_barrier();
    // ---------- phase 3: issue A(t+2); MFMA mi4-7 x ni2-3; counted vmcnt
    if (t + 2 < NT) issueA(t + 2);
    __builtin_amdgcn_s_barrier();
    __builtin_amdgcn_s_setprio(1);
#pragma unroll
    for (int mi = 0; mi < 4; ++mi)
#pragma unroll
      for (int ni = 2; ni < 4; ++ni) {
        MFMA_(acc[mi + 4][ni], af[mi][0], bfr[ni][0]);
        MFMA_(acc[mi + 4][ni], af[mi][1], bfr[ni][1]);
      }
    __builtin_amdgcn_s_setprio(0);
    if (t + 2 < NT) { asm volatile("s_waitcnt vmcnt(8)" ::: "memory"); }
    else            { asm volatile("s_waitcnt vmcnt(0)" ::: "memory"); }
    __builtin_amdgcn_s_barrier();
  };

  for (int t = 0; t < NT; t += 2) { step(t, 0); step(t + 1, 1); }

  // ---------- epilogue ----------
  const int c0 = lane & 15;
  const int r0 = (lane >> 4) << 2;
  if constexpr (EPI == EPI_SCALE) {
    unsigned short* Cz = p.C + (long long)z * p.batchC;
#pragma unroll
    for (int mi = 0; mi < 8; ++mi) {
      const int grow = m0 + (wm << 7) + (mi << 4) + r0;
#pragma unroll
      for (int ni = 0; ni < 4; ++ni) {
        const int gcol = n0 + (wn << 6) + (ni << 4) + c0;
#pragma unroll
        for (int rr = 0; rr < 4; ++rr)
          Cz[(long long)(grow + rr) * p.ldc + gcol] = f2bf(acc[mi][ni][rr] * p.scale);
      }
    }
  } else { // EPI_PROJ
    if (z < 2) {
      unsigned short* O = (z == 0) ? p.outQ : p.outK;
      const float* bias = (z == 0) ? p.biasQ : p.biasK;
#pragma unroll
      for (int mi = 0; mi < 8; ++mi) {
        const int grow = m0 + (wm << 7) + (mi << 4) + r0;
#pragma unroll
        for (int ni = 0; ni < 4; ++ni) {
          const int gcol = n0 + (wn << 6) + (ni << 4) + c0;
          const float bb = bias[gcol];
#pragma unroll
          for (int rr = 0; rr < 4; ++rr)
            O[(long long)(grow + rr) * 1024 + gcol] = f2bf(acc[mi][ni][rr] + bb);
        }
      }
    } else { // v projection, transposed out: vT[b][d][s]
#pragma unroll
      for (int mi = 0; mi < 8; ++mi) {
        const int grow = m0 + (wm << 7) + (mi << 4) + r0;
        const int bb = grow >> 11, s = grow & 2047;
#pragma unroll
        for (int ni = 0; ni < 4; ++ni) {
          const int d = n0 + (wn << 6) + (ni << 4) + c0;
          const float ba = p.biasV[d];
          ushort4 pk;
          pk.x = f2bf(acc[mi][ni][0] + ba);
          pk.y = f2bf(acc[mi][ni][1] + ba);
          pk.z = f2bf(acc[mi][ni][2] + ba);
          pk.w = f2bf(acc[mi][ni][3] + ba);
          *(ushort4*)(p.outV + ((long long)bb << 21) + (long long)d * 2048 + s) = pk;
        }
      }
    }
  }
}

// =====================================================================
// legacy 128x128 GEMM (kept for PV: 512 WGs fill the chip there)
// =====================================================================
#define EPI_OUT 3

template<int EPI>
__global__ __launch_bounds__(256, 2) void gemm_bt(
    const unsigned short* __restrict__ A,
    const unsigned short* __restrict__ B,
    void* __restrict__ Cv,
    const float* __restrict__ bias,
    int lda, int ldb, int ldc, int K, float scale,
    long long batchA, long long batchB, long long batchC)
{
  __shared__ unsigned short sA[128 * 64];
  __shared__ unsigned short sB[128 * 64];
  const int tid = threadIdx.x;
  const int lane = tid & 63;
  const int wave = tid >> 6;
  const int wm = wave >> 1, wn = wave & 1;
  const int z = blockIdx.z;
  const int m0 = blockIdx.y * 128, n0 = blockIdx.x * 128;

  const char* Ab = (const char*)(A + (long long)z * batchA + (long long)m0 * lda);
  const char* Bb = (const char*)(B + (long long)z * batchB + (long long)n0 * ldb);
  const int lda2 = lda * 2, ldb2 = ldb * 2;

  f32x4 acc[4][4];
#pragma unroll
  for (int i = 0; i < 4; ++i)
#pragma unroll
    for (int j = 0; j < 4; ++j) acc[i][j] = (f32x4){0.f, 0.f, 0.f, 0.f};

  const int laneoff = (lane & 15) * 128 + (lane >> 4) * 16;

  const int nkt = K >> 6;
  for (int kt = 0; kt < nkt; ++kt) {
    const int kb = kt * 128;
#pragma unroll
    for (int i = 0; i < 4; ++i) {
      unsigned o = (unsigned)(i * 4096 + wave * 1024 + lane * 16);
      unsigned row = o >> 7, cb = o & 127u;
      G2L(Ab + (long long)row * lda2 + kb + cb, (char*)sA + i * 4096 + wave * 1024);
      G2L(Bb + (long long)row * ldb2 + kb + cb, (char*)sB + i * 4096 + wave * 1024);
    }
    __syncthreads();

    const char* sAc = (const char*)sA;
    const char* sBc = (const char*)sB;
#pragma unroll
    for (int kk = 0; kk < 2; ++kk) {
      bf16x8 af[4], bfr[4];
#pragma unroll
      for (int mi = 0; mi < 4; ++mi)
        af[mi] = *(const bf16x8*)(sAc + (wm * 64 + mi * 16) * 128 + kk * 64 + laneoff);
#pragma unroll
      for (int ni = 0; ni < 4; ++ni)
        bfr[ni] = *(const bf16x8*)(sBc + (wn * 64 + ni * 16) * 128 + kk * 64 + laneoff);
#pragma unroll
      for (int mi = 0; mi < 4; ++mi)
#pragma unroll
        for (int ni = 0; ni < 4; ++ni)
          acc[mi][ni] = __builtin_amdgcn_mfma_f32_16x16x32_bf16(af[mi], bfr[ni], acc[mi][ni], 0, 0, 0);
    }
    __syncthreads();
  }

  const int col16 = lane & 15;
  const int r0 = (lane >> 4) * 4;
#pragma unroll
  for (int mi = 0; mi < 4; ++mi) {
#pragma unroll
    for (int ni = 0; ni < 4; ++ni) {
      const int gcol = n0 + wn * 64 + ni * 16 + col16;
#pragma unroll
      for (int rr = 0; rr < 4; ++rr) {
        const int grow = m0 + wm * 64 + mi * 16 + r0 + rr;
        const float val = acc[mi][ni][rr] * scale;
        const size_t off = (size_t)z * batchC + (size_t)grow * ldc + gcol;
        ((float*)Cv)[off] = val;
      }
    }
  }
}

// ---------- row softmax over S[4][2048][2048] (bf16, in place) ----------
__global__ __launch_bounds__(256) void softmax_rows(unsigned short* __restrict__ S) {
  const size_t row = blockIdx.x;
  unsigned short* pp = S + row * 2048;
  const int t = threadIdx.x, lane = t & 63, wave = t >> 6;
  u16x8 h = ((const u16x8*)pp)[t];
  float x[8];
#pragma unroll
  for (int j = 0; j < 8; ++j) x[j] = bf2f(h[j]);
  float m = x[0];
#pragma unroll
  for (int j = 1; j < 8; ++j) m = fmaxf(m, x[j]);
#pragma unroll
  for (int off = 32; off >= 1; off >>= 1) m = fmaxf(m, __shfl_xor(m, off, 64));
  __shared__ float rmax[4], rsum[4];
  if (lane == 0) rmax[wave] = m;
  __syncthreads();
  m = fmaxf(fmaxf(rmax[0], rmax[1]), fmaxf(rmax[2], rmax[3]));
  float e[8], sum = 0.f;
#pragma unroll
  for (int j = 0; j < 8; ++j) { e[j] = __expf(x[j] - m); sum += e[j]; }
#pragma unroll
  for (int off = 32; off >= 1; off >>= 1) sum += __shfl_xor(sum, off, 64);
  if (lane == 0) rsum[wave] = sum;
  __syncthreads();
  sum = rsum[0] + rsum[1] + rsum[2] + rsum[3];
  const float inv = 1.f / sum;
  u16x8 o;
#pragma unroll
  for (int j = 0; j < 8; ++j) o[j] = f2bf(e[j] * inv);
  ((u16x8*)pp)[t] = o;
}

// ---------- launch ----------
extern "C" void kernel_launch(void* const* d_in, const int* in_sizes, int n_in,
                              void* d_out, int out_size, void* d_ws, size_t ws_size,
                              hipStream_t stream) {
  const float* q  = (const float*)d_in[0];
  const float* k  = (const float*)d_in[1];
  const float* v  = (const float*)d_in[2];
  const float* Wq = (const float*)d_in[3];
  const float* bq = (const float*)d_in[4];
  const float* Wk = (const float*)d_in[5];
  const float* bk = (const float*)d_in[6];
  const float* Wv = (const float*)d_in[7];
  const float* bv = (const float*)d_in[8];

  // workspace (u16 elems): Xb 48MB (S 32MB overlays it later), Wb 6MB,
  // qb 16MB, kb 16MB, vT 16MB -> 102MB total
  unsigned short* Xb = (unsigned short*)d_ws;
  unsigned short* Wb = Xb + 25165824;
  unsigned short* qb = Wb + 3145728;
  unsigned short* kb = qb + 8388608;
  unsigned short* vT = kb + 8388608;
  unsigned short* S  = Xb;

  (void)hipFuncSetAttribute((const void*)gemm256<EPI_PROJ>,
      hipFuncAttributeMaxDynamicSharedMemorySize, 131072);
  (void)hipFuncSetAttribute((const void*)gemm256<EPI_SCALE>,
      hipFuncAttributeMaxDynamicSharedMemorySize, 131072);

  CvtArgs ca;
  ca.src[0] = q;  ca.src[1] = k;  ca.src[2] = v;
  ca.src[3] = Wq; ca.src[4] = Wk; ca.src[5] = Wv;
  ca.dst[0] = Xb;            ca.dst[1] = Xb + 8388608; ca.dst[2] = Xb + 16777216;
  ca.dst[3] = Wb;            ca.dst[4] = Wb + 1048576; ca.dst[5] = Wb + 2097152;
  cvt6<<<27648, 256, 0, stream>>>(ca);

  // fused q/k/v projections: per z, M=8192, N=1024, K=1024
  G256 gp{};
  gp.A = Xb;  gp.batchA = 8388608; gp.lda = 1024;
  gp.B = Wb;  gp.batchB = 1048576; gp.ldb = 1024;
  gp.outQ = qb; gp.outK = kb; gp.outV = vT;
  gp.biasQ = bq; gp.biasK = bk; gp.biasV = bv;
  gp.K = 1024; gp.scale = 1.f;
  gemm256<EPI_PROJ><<<dim3(4, 32, 3), 512, 131072, stream>>>(gp);

  // scores = q @ k^T * scale : per batch M=2048, N=2048, K=1024
  G256 gs{};
  gs.A = qb; gs.batchA = 2097152; gs.lda = 1024;
  gs.B = kb; gs.batchB = 2097152; gs.ldb = 1024;
  gs.C = S;  gs.batchC = 4194304; gs.ldc = 2048;
  gs.K = 1024; gs.scale = 0.03125f;
  gemm256<EPI_SCALE><<<dim3(8, 8, 4), 512, 131072, stream>>>(gs);

  softmax_rows<<<8192, 256, 0, stream>>>(S);

  // out = P @ V : M=2048, N=1024, K=2048 per batch (128^2 kernel, 512 WGs)
  gemm_bt<EPI_OUT><<<dim3(8, 16, 4), 256, 0, stream>>>(
      S, vT, (float*)d_out, nullptr, 2048, 2048, 1024, 2048, 1.f,
      4194304LL, 2097152LL, 2097152LL);
}